// Round 3
// baseline (49.437 us; speedup 1.0000x reference)
//
#include <hip/hip_runtime.h>
#include <math.h>

// MXFP8_E4M3 quant-dequant, E8M0 shared scale, BLOCK=32, fp32 in/out.
//
// Exact-math formulation: scale = 2^S with S = floor(log2(amax)) - 3.
// Quant-dequant of x is snapping to ulp grid 2^g with
//   g = max(floor(log2|x|) - 3, S - 9)
// (S-9 encodes the E4M3 emin=-6 ulp clamp pulled back through the scale).
// rintf == round-half-to-even == jnp.round. ldexpf/frexpf are exact.
// E4M3 xmax=240 clip can never fire since |x/scale| < 16.
//
// R2: same nt-hint experiment as R1, but with a native clang vector type —
// __builtin_nontemporal_* rejects HIP_vector_type structs.

typedef float f32x4 __attribute__((ext_vector_type(4)));

__device__ __forceinline__ float quant_elem(float x, int Sm9) {
    int e2;
    (void)frexpf(x, &e2);                 // |x| = m * 2^e2, m in [0.5,1); x==0 -> e2=0 (safe)
    int g = e2 - 4;                        // floor(log2|x|) - 3  (= e2 - 1 - 3)
    if (g < Sm9) g = Sm9;                  // emin clamp of E4M3 subnormal grid
    float r = rintf(ldexpf(x, -g));        // round-half-even on the 2^g grid
    return ldexpf(r, g);
}

__global__ __launch_bounds__(256) void mxq_kernel(const float* __restrict__ x,
                                                  float* __restrict__ out,
                                                  int n4) {
    const float INF = __builtin_huge_valf();
    int idx = blockIdx.x * blockDim.x + threadIdx.x;
    int stride = gridDim.x * blockDim.x;
    for (int i = idx; i < n4; i += stride) {
        f32x4 v = __builtin_nontemporal_load(reinterpret_cast<const f32x4*>(x) + i);

        // per-thread amax of 4 elems; NaN -> Inf so invalid blocks are flagged
        // (fminf(NaN, INF) = INF; Inf stays Inf; finite stays finite)
        float a0 = fminf(fabsf(v.x), INF);
        float a1 = fminf(fabsf(v.y), INF);
        float a2 = fminf(fabsf(v.z), INF);
        float a3 = fminf(fabsf(v.w), INF);
        float m = fmaxf(fmaxf(a0, a1), fmaxf(a2, a3));

        // 8 consecutive lanes = one MX block of 32 elements.
        // xor masks 1,2,4 stay inside aligned 8-lane groups of the wave64.
        m = fmaxf(m, __shfl_xor(m, 1));
        m = fmaxf(m, __shfl_xor(m, 2));
        m = fmaxf(m, __shfl_xor(m, 4));

        bool valid = (m > 0.0f) && (m < INF);   // amax>0 && isfinite(amax)

        int e2m = 0;
        if (valid) (void)frexpf(m, &e2m);
        int S = e2m - 4;                        // floor(log2(amax)) - 3
        if (S < -127) valid = false;            // E8M0 chop -> scale 0 -> block zeros
        if (S == -127) S = -126;                // RN bumps to smallest normal

        f32x4 o;
        if (valid) {
            int Sm9 = S - 9;
            o.x = quant_elem(v.x, Sm9);
            o.y = quant_elem(v.y, Sm9);
            o.z = quant_elem(v.z, Sm9);
            o.w = quant_elem(v.w, Sm9);
        } else {
            o = (f32x4)0.0f;
        }
        __builtin_nontemporal_store(o, reinterpret_cast<f32x4*>(out) + i);
    }
}

extern "C" void kernel_launch(void* const* d_in, const int* in_sizes, int n_in,
                              void* d_out, int out_size, void* d_ws, size_t ws_size,
                              hipStream_t stream) {
    const float* x = (const float*)d_in[0];
    float* out = (float*)d_out;
    int n = in_sizes[0];
    int n4 = n >> 2;                       // n = 4096*8192, divisible by 4
    int block = 256;
    int grid = (n4 + block - 1) / block;
    if (grid > 2048) grid = 2048;          // grid-stride; 8 blocks/CU on 256 CUs
    mxq_kernel<<<grid, block, 0, stream>>>(x, out, n4);
}

// Round 4
// 44.648 us; speedup vs baseline: 1.1073x; 1.1073x over previous
//
#include <hip/hip_runtime.h>
#include <math.h>

// MXFP8_E4M3 quant-dequant, E8M0 shared scale, BLOCK=32, fp32 in/out.
//
// Exact-math formulation: scale = 2^S with S = floor(log2(amax)) - 3.
// Quant-dequant of x is snapping to ulp grid 2^g with
//   g = max(floor(log2|x|) - 3, S - 9)
// (S-9 encodes the E4M3 emin=-6 ulp clamp pulled back through the scale).
// rintf == round-half-to-even == jnp.round. ldexpf/frexpf are exact.
// E4M3 xmax=240 clip can never fire since |x/scale| < 16.
//
// R2 post-mortem: nontemporal hints REGRESSED (45.2 -> 49.4 us) — on gfx950
// the L2/L3 help drain a mixed R/W stream; do not bypass. Reverted.
// R3 change (isolated): 8 floats/thread (2 independent dwordx4 loads) for
// 2x memory-level parallelism per wave; 4 lanes = one MX block, so the
// amax reduce needs only 2 shuffles (xor 1,2).

typedef float f32x4 __attribute__((ext_vector_type(4)));

__device__ __forceinline__ float quant_elem(float x, int Sm9) {
    int e2;
    (void)frexpf(x, &e2);                 // |x| = m * 2^e2, m in [0.5,1); x==0 -> e2=0 (safe)
    int g = e2 - 4;                        // floor(log2|x|) - 3  (= e2 - 1 - 3)
    if (g < Sm9) g = Sm9;                  // emin clamp of E4M3 subnormal grid
    float r = rintf(ldexpf(x, -g));        // round-half-even on the 2^g grid
    return ldexpf(r, g);
}

__global__ __launch_bounds__(256) void mxq_kernel(const float* __restrict__ x,
                                                  float* __restrict__ out,
                                                  int n8) {
    const float INF = __builtin_huge_valf();
    int idx = blockIdx.x * blockDim.x + threadIdx.x;
    int stride = gridDim.x * blockDim.x;
    for (int i = idx; i < n8; i += stride) {
        const f32x4* p = reinterpret_cast<const f32x4*>(x) + 2 * (size_t)i;
        f32x4 v0 = p[0];                   // two independent 16B loads -> 2x MLP
        f32x4 v1 = p[1];

        // per-thread amax of 8 elems; NaN -> Inf so invalid blocks are flagged
        // (fminf(NaN, INF) = INF; Inf stays Inf; finite stays finite)
        float m = fminf(fabsf(v0.x), INF);
        m = fmaxf(m, fminf(fabsf(v0.y), INF));
        m = fmaxf(m, fminf(fabsf(v0.z), INF));
        m = fmaxf(m, fminf(fabsf(v0.w), INF));
        m = fmaxf(m, fminf(fabsf(v1.x), INF));
        m = fmaxf(m, fminf(fabsf(v1.y), INF));
        m = fmaxf(m, fminf(fabsf(v1.z), INF));
        m = fmaxf(m, fminf(fabsf(v1.w), INF));

        // 4 consecutive lanes = one MX block of 32 elements.
        // xor masks 1,2 stay inside aligned 4-lane groups of the wave64.
        m = fmaxf(m, __shfl_xor(m, 1));
        m = fmaxf(m, __shfl_xor(m, 2));

        bool valid = (m > 0.0f) && (m < INF);   // amax>0 && isfinite(amax)

        int e2m = 0;
        if (valid) (void)frexpf(m, &e2m);
        int S = e2m - 4;                        // floor(log2(amax)) - 3
        if (S < -127) valid = false;            // E8M0 chop -> scale 0 -> block zeros
        if (S == -127) S = -126;                // RN bumps to smallest normal

        f32x4 o0, o1;
        if (valid) {
            int Sm9 = S - 9;
            o0.x = quant_elem(v0.x, Sm9);
            o0.y = quant_elem(v0.y, Sm9);
            o0.z = quant_elem(v0.z, Sm9);
            o0.w = quant_elem(v0.w, Sm9);
            o1.x = quant_elem(v1.x, Sm9);
            o1.y = quant_elem(v1.y, Sm9);
            o1.z = quant_elem(v1.z, Sm9);
            o1.w = quant_elem(v1.w, Sm9);
        } else {
            o0 = (f32x4)0.0f;
            o1 = (f32x4)0.0f;
        }
        f32x4* q = reinterpret_cast<f32x4*>(out) + 2 * (size_t)i;
        q[0] = o0;
        q[1] = o1;
    }
}

extern "C" void kernel_launch(void* const* d_in, const int* in_sizes, int n_in,
                              void* d_out, int out_size, void* d_ws, size_t ws_size,
                              hipStream_t stream) {
    const float* x = (const float*)d_in[0];
    float* out = (float*)d_out;
    int n = in_sizes[0];
    int n8 = n >> 3;                       // n = 4096*8192, divisible by 8
    int block = 256;
    int grid = (n8 + block - 1) / block;
    if (grid > 2048) grid = 2048;          // grid-stride; 8 blocks/CU on 256 CUs
    mxq_kernel<<<grid, block, 0, stream>>>(x, out, n8);
}